// Round 7
// baseline (276.078 us; speedup 1.0000x reference)
//
#include <hip/hip_runtime.h>
#include <hip/hip_bf16.h>

#define S 2048
#define H 1024
#define NH 16
#define DH 64
#define RV 32
#define BK 32

typedef __hip_bfloat16 bf16;
typedef short bf16x8 __attribute__((ext_vector_type(8)));
typedef float f32x4 __attribute__((ext_vector_type(4)));

__device__ __forceinline__ float b2f(bf16 v) { return __bfloat162float(v); }
__device__ __forceinline__ unsigned short f2bbits(float x) {
    __hip_bfloat16 b = __float2bfloat16(x);
    return *reinterpret_cast<unsigned short*>(&b);
}
// Flexible load: f==1 -> buffer holds fp32, f==0 -> buffer holds bf16.
__device__ __forceinline__ float ldf(const void* p, int i, int f) {
    return f ? ((const float*)p)[i] : b2f(((const bf16*)p)[i]);
}
// async 16B global -> LDS (lane l lands at lds_base + l*16)
__device__ __forceinline__ void gl_lds16(const bf16* g, bf16* l) {
    __builtin_amdgcn_global_load_lds(
        (const __attribute__((address_space(1))) void*)g,
        (__attribute__((address_space(3))) void*)l,
        16, 0, 0);
}

// ---------------- dtype sniffer -------------------------------------------
__global__ void detect_dtype(const unsigned int* __restrict__ xw,
                             int* __restrict__ flag)
{
    __shared__ int cnt;
    if (threadIdx.x == 0) cnt = 0;
    __syncthreads();
    unsigned int w = xw[threadIdx.x];
    unsigned int ex = ((w & 0xffffu) >> 7) & 0xffu;
    int big = (ex > 134u) ? 1 : 0;
    #pragma unroll
    for (int off = 32; off > 0; off >>= 1) big += __shfl_xor(big, off, 64);
    if ((threadIdx.x & 63) == 0) atomicAdd(&cnt, big);
    __syncthreads();
    if (threadIdx.x == 0) *flag = (cnt > 60) ? 1 : 0;
}

// ---------------- pack rel_ids + att_mask into one byte --------------------
// pb = rid | (mask==0)<<7.  33.5 MB -> 4.2 MB; read once instead of 16x.
__global__ __launch_bounds__(256) void pack_rm(
    const int* __restrict__ rel_ids, const int* __restrict__ att_mask,
    unsigned char* __restrict__ PBg)
{
    int i = blockIdx.x * 256 + threadIdx.x;
    int4 rid = ((const int4*)rel_ids)[i];
    int4 msk = ((const int4*)att_mask)[i];
    uchar4 o;
    o.x = (unsigned char)(rid.x | ((msk.x == 0) << 7));
    o.y = (unsigned char)(rid.y | ((msk.y == 0) << 7));
    o.z = (unsigned char)(rid.z | ((msk.z == 0) << 7));
    o.w = (unsigned char)(rid.w | ((msk.w == 0) << 7));
    ((uchar4*)PBg)[i] = o;
}

// ---------------- input conversion ----------------------------------------
__global__ __launch_bounds__(256) void convert_x(
    const void* __restrict__ x, bf16* __restrict__ xb,
    const int* __restrict__ flag)
{
    const int i = (blockIdx.x * 256 + threadIdx.x) * 4;
    if (*flag) {
        float4 v = ((const float4*)x)[i >> 2];
        ushort4 o;
        o.x = f2bbits(v.x); o.y = f2bbits(v.y);
        o.z = f2bbits(v.z); o.w = f2bbits(v.w);
        *(ushort4*)&xb[i] = o;
    } else {
        ((ushort4*)xb)[i >> 2] = ((const ushort4*)x)[i >> 2];
    }
}

// transpose-convert weights: W[k][n] (fp32 or bf16) -> WT[n][k] bf16
__global__ __launch_bounds__(256) void wtrans(
    const void* __restrict__ W0, const void* __restrict__ W1,
    const void* __restrict__ W2, const void* __restrict__ W3,
    bf16* __restrict__ T0, bf16* __restrict__ T1,
    bf16* __restrict__ T2, bf16* __restrict__ T3,
    const int* __restrict__ flag)
{
    const void* W; bf16* T;
    switch (blockIdx.z) {
        case 0:  W = W0; T = T0; break;
        case 1:  W = W1; T = T1; break;
        case 2:  W = W2; T = T2; break;
        default: W = W3; T = T3; break;
    }
    const int f = *flag;
    __shared__ unsigned short Ts[64][68];
    const int t = threadIdx.x;
    const int tx = t & 15, ty = t >> 4;
    const int n0 = blockIdx.x * 64;
    const int k0 = blockIdx.y * 64;
    #pragma unroll
    for (int it = 0; it < 4; ++it) {
        int k = ty + it * 16;
        int base = (k0 + k) * H + n0 + tx * 4;
        #pragma unroll
        for (int e = 0; e < 4; ++e)
            Ts[k][tx * 4 + e] = f2bbits(ldf(W, base + e, f));
    }
    __syncthreads();
    #pragma unroll
    for (int it = 0; it < 4; ++it) {
        int n = ty + it * 16;
        ushort4 o;
        o.x = Ts[tx * 4 + 0][n];
        o.y = Ts[tx * 4 + 1][n];
        o.z = Ts[tx * 4 + 2][n];
        o.w = Ts[tx * 4 + 3][n];
        *(ushort4*)&T[(size_t)(n0 + n) * H + k0 + tx * 4] = o;
    }
}

// transpose Vb[S][H] bf16 -> VT[H][S] bf16
__global__ __launch_bounds__(256) void vtrans(
    const bf16* __restrict__ Vb, bf16* __restrict__ VT)
{
    __shared__ unsigned short Ts[64][68];
    const int t = threadIdx.x;
    const int tx = t & 15, ty = t >> 4;
    const int s0 = blockIdx.x * 64;
    const int h0 = blockIdx.y * 64;
    #pragma unroll
    for (int it = 0; it < 4; ++it) {
        int s = ty + it * 16;
        *(ushort4*)&Ts[s][tx * 4] =
            *(const ushort4*)&Vb[(size_t)(s0 + s) * H + h0 + tx * 4];
    }
    __syncthreads();
    #pragma unroll
    for (int it = 0; it < 4; ++it) {
        int hh = ty + it * 16;
        ushort4 o;
        o.x = Ts[tx * 4 + 0][hh];
        o.y = Ts[tx * 4 + 1][hh];
        o.z = Ts[tx * 4 + 2][hh];
        o.w = Ts[tx * 4 + 3][hh];
        *(ushort4*)&VT[(size_t)(h0 + hh) * S + s0 + tx * 4] = o;
    }
}

// ---------------- m97-style 128x128 MFMA GEMM core -------------------------
__device__ __forceinline__ void gemm128_bt(
    const bf16* __restrict__ A, const bf16* __restrict__ BT,
    f32x4 (&acc)[4][4])
{
    const int tid = threadIdx.x;
    const int w = tid >> 6, lane = tid & 63;
    const int l15 = lane & 15, quad = lane >> 4;
    const int wm = (w & 1) * 64, wn = (w >> 1) * 64;
    const int rowb = blockIdx.y * 128;
    const int colb = blockIdx.x * 128;

    __shared__ bf16 As[128 * BK];   // [m][k], rows of 32 bf16 (64 B)
    __shared__ bf16 Bs[128 * BK];   // [n][k]

    for (int kb = 0; kb < H; kb += BK) {
        #pragma unroll
        for (int j = 0; j < 2; ++j) {
            int i = j * 256 + w * 64 + lane;
            gl_lds16(&A[(size_t)(rowb + (i >> 2)) * H + kb + (i & 3) * 8],
                     &As[(size_t)(j * 256 + w * 64) * 8]);
            gl_lds16(&BT[(size_t)(colb + (i >> 2)) * H + kb + (i & 3) * 8],
                     &Bs[(size_t)(j * 256 + w * 64) * 8]);
        }
        __syncthreads();

        bf16x8 af[4], bfr[4];
        #pragma unroll
        for (int mt = 0; mt < 4; ++mt)
            af[mt] = *(const bf16x8*)&As[(wm + mt * 16 + l15) * BK + quad * 8];
        #pragma unroll
        for (int nt = 0; nt < 4; ++nt)
            bfr[nt] = *(const bf16x8*)&Bs[(wn + nt * 16 + l15) * BK + quad * 8];
        #pragma unroll
        for (int mt = 0; mt < 4; ++mt)
            #pragma unroll
            for (int nt = 0; nt < 4; ++nt)
                acc[mt][nt] = __builtin_amdgcn_mfma_f32_16x16x32_bf16(
                    af[mt], bfr[nt], acc[mt][nt], 0, 0, 0);
        __syncthreads();
    }
}

// ---------------- QKV MFMA GEMM -------------------------------------------
__global__ __launch_bounds__(256) void qkv_mfma(
    const bf16* __restrict__ xb,
    const bf16* __restrict__ WTq, const bf16* __restrict__ WTk,
    const bf16* __restrict__ WTv,
    const void* __restrict__ bq, const void* __restrict__ bk,
    const void* __restrict__ bv,
    bf16* __restrict__ Qb, bf16* __restrict__ Kb, bf16* __restrict__ Vb,
    const int* __restrict__ flag)
{
    const bf16* BT; const void* bias; bf16* out;
    if (blockIdx.z == 0)      { BT = WTq; bias = bq; out = Qb; }
    else if (blockIdx.z == 1) { BT = WTk; bias = bk; out = Kb; }
    else                      { BT = WTv; bias = bv; out = Vb; }
    const int f = *flag;

    f32x4 acc[4][4];
    #pragma unroll
    for (int a = 0; a < 4; ++a)
        #pragma unroll
        for (int b = 0; b < 4; ++b) acc[a][b] = (f32x4)0.f;

    gemm128_bt(xb, BT, acc);

    const int tid = threadIdx.x;
    const int w = tid >> 6, lane = tid & 63;
    const int l15 = lane & 15, quad = lane >> 4;
    const int wm = (w & 1) * 64, wn = (w >> 1) * 64;
    const int rowb = blockIdx.y * 128;
    const int colb = blockIdx.x * 128;

    float bvv[4];
    #pragma unroll
    for (int nt = 0; nt < 4; ++nt)
        bvv[nt] = ldf(bias, colb + wn + nt * 16 + l15, f);

    #pragma unroll
    for (int mt = 0; mt < 4; ++mt)
        #pragma unroll
        for (int nt = 0; nt < 4; ++nt)
            #pragma unroll
            for (int r = 0; r < 4; ++r) {
                int m = rowb + wm + mt * 16 + quad * 4 + r;
                int n = colb + wn + nt * 16 + l15;
                out[(size_t)m * H + n] = __float2bfloat16(acc[mt][nt][r] + bvv[nt]);
            }
}

// ---------------- output MFMA GEMM ----------------------------------------
__global__ __launch_bounds__(256) void out_mfma(
    const bf16* __restrict__ Cb, const bf16* __restrict__ WoT,
    const void* __restrict__ bias, void* __restrict__ out,
    const int* __restrict__ flag)
{
    const int f = *flag;
    f32x4 acc[4][4];
    #pragma unroll
    for (int a = 0; a < 4; ++a)
        #pragma unroll
        for (int b = 0; b < 4; ++b) acc[a][b] = (f32x4)0.f;

    gemm128_bt(Cb, WoT, acc);

    const int tid = threadIdx.x;
    const int w = tid >> 6, lane = tid & 63;
    const int l15 = lane & 15, quad = lane >> 4;
    const int wm = (w & 1) * 64, wn = (w >> 1) * 64;
    const int rowb = blockIdx.y * 128;
    const int colb = blockIdx.x * 128;

    float bvv[4];
    #pragma unroll
    for (int nt = 0; nt < 4; ++nt)
        bvv[nt] = ldf(bias, colb + wn + nt * 16 + l15, f);

    #pragma unroll
    for (int mt = 0; mt < 4; ++mt)
        #pragma unroll
        for (int nt = 0; nt < 4; ++nt)
            #pragma unroll
            for (int r = 0; r < 4; ++r) {
                int m = rowb + wm + mt * 16 + quad * 4 + r;
                int n = colb + wn + nt * 16 + l15;
                float v = acc[mt][nt][r] + bvv[nt];
                if (f) ((float*)out)[(size_t)m * H + n] = v;
                else   ((bf16*)out)[(size_t)m * H + n] = __float2bfloat16(v);
            }
}

// ---------------- MFMA flash attention (rel fused, packed bias, pipelined) --
// block = (64 queries) x (1 head), 4 waves; wave w owns q rows w*16..w*16+15.
// Q pre-scaled by 0.125 (exact exponent shift), Rl pre-scaled incl rel_bias.
// LDS ~39.9 KB -> 4 blocks/CU.
__global__ __launch_bounds__(256, 4) void attn_mfma(
    const bf16* __restrict__ Qb, const bf16* __restrict__ Kb,
    const bf16* __restrict__ VT,
    const void* __restrict__ rel_emb, const void* __restrict__ rel_bias,
    const unsigned char* __restrict__ PBg,
    bf16* __restrict__ Cb, const int* __restrict__ flag)
{
    const int h = blockIdx.x;
    const int q0 = blockIdx.y * 64;
    const int tid = threadIdx.x;
    const int w = tid >> 6;
    const int lane = tid & 63;
    const int l15 = lane & 15;
    const int quad = lane >> 4;
    const int f = *flag;

    __shared__ short Ks[64][72];
    __shared__ short Vs[64][72];
    __shared__ float Rl[64][33];     // pre-scaled rel scores (incl bias/8)
    __shared__ float Rbias[32];
    union SharedU {
        struct { short Qs[64][72]; short Es[32][72]; } init;
        struct { short Ps[64][72]; unsigned char PB[64][64]; } main;
    };
    __shared__ SharedU U;

    // ---- prefetch tile 0 into registers (start latency early) ----
    uint4 kp[2], vp[2], pbp;
    {
        #pragma unroll
        for (int j = 0; j < 2; ++j) {
            int slot = j * 256 + tid;
            int r = slot >> 3, c = slot & 7;
            kp[j] = *(const uint4*)&Kb[(size_t)r * H + h * DH + c * 8];
            vp[j] = *(const uint4*)&VT[(size_t)(h * DH + r) * S + c * 8];
        }
        int pq = tid >> 2, pc = (tid & 3) * 16;
        pbp = *(const uint4*)&PBg[(size_t)(q0 + pq) * S + pc];
    }

    // ---- stage Q (scaled by 0.125) + rel_emb + rel_bias ----
    for (int slot = tid; slot < 512; slot += 256) {
        int q = slot >> 3, c = slot & 7;
        uint4 raw = *(const uint4*)&Qb[(size_t)(q0 + q) * H + h * DH + c * 8];
        const unsigned short* rs = (const unsigned short*)&raw;
        unsigned short os[8];                       // FIX: proper 8-elem array
        #pragma unroll
        for (int e = 0; e < 8; ++e) {
            float v; *((unsigned int*)&v) = ((unsigned int)rs[e]) << 16;
            os[e] = f2bbits(v * 0.125f);            // exact: exponent shift
        }
        *(ushort4*)&U.init.Qs[q][c * 8]     = *(ushort4*)&os[0];
        *(ushort4*)&U.init.Qs[q][c * 8 + 4] = *(ushort4*)&os[4];
    }
    {
        int r = tid >> 3, c8 = (tid & 7) * 8;
        if (f) {
            const float* src = (const float*)rel_emb + (r * NH + h) * DH + c8;
            ushort4 o0, o1;
            o0.x = f2bbits(src[0]); o0.y = f2bbits(src[1]);
            o0.z = f2bbits(src[2]); o0.w = f2bbits(src[3]);
            o1.x = f2bbits(src[4]); o1.y = f2bbits(src[5]);
            o1.z = f2bbits(src[6]); o1.w = f2bbits(src[7]);
            *(ushort4*)&U.init.Es[r][c8] = o0;
            *(ushort4*)&U.init.Es[r][c8 + 4] = o1;
        } else {
            *(uint4*)&U.init.Es[r][c8] =
                *(const uint4*)((const bf16*)rel_emb + (r * NH + h) * DH + c8);
        }
        if (tid < RV) Rbias[tid] = ldf(rel_bias, tid * NH + h, f) * 0.125f;
    }
    __syncthreads();

    // ---- Q fragments (scaled; reused everywhere) ----
    bf16x8 aq0 = *(const bf16x8*)&U.init.Qs[w * 16 + l15][quad * 8];
    bf16x8 aq1 = *(const bf16x8*)&U.init.Qs[w * 16 + l15][32 + quad * 8];

    // ---- Rl[q][r] = (Q/8) . rel_emb^T + rel_bias/8 via MFMA ----
    #pragma unroll
    for (int nt = 0; nt < 2; ++nt) {
        bf16x8 be0 = *(const bf16x8*)&U.init.Es[nt * 16 + l15][quad * 8];
        bf16x8 be1 = *(const bf16x8*)&U.init.Es[nt * 16 + l15][32 + quad * 8];
        f32x4 c = (f32x4)0.f;
        c = __builtin_amdgcn_mfma_f32_16x16x32_bf16(aq0, be0, c, 0, 0, 0);
        c = __builtin_amdgcn_mfma_f32_16x16x32_bf16(aq1, be1, c, 0, 0, 0);
        float rb = Rbias[nt * 16 + l15];
        #pragma unroll
        for (int r = 0; r < 4; ++r)
            Rl[w * 16 + quad * 4 + r][nt * 16 + l15] = c[r] + rb;
    }
    __syncthreads();   // everyone done with Qs/Es before PB overwrites them

    f32x4 O[4];
    float mrow[4], lrow[4];
    #pragma unroll
    for (int i = 0; i < 4; ++i) { O[i] = (f32x4)0.f; mrow[i] = -1e30f; lrow[i] = 0.f; }

    const int pq = tid >> 2, pc = (tid & 3) * 16;

    for (int kt = 0; kt < S; kt += 64) {
        // ---- store prefetched tile to LDS ----
        #pragma unroll
        for (int j = 0; j < 2; ++j) {
            int slot = j * 256 + tid;
            int r = slot >> 3, c = slot & 7;
            *(uint4*)&Ks[r][c * 8] = kp[j];
            *(uint4*)&Vs[r][c * 8] = vp[j];
        }
        *(uint4*)&U.main.PB[pq][pc] = pbp;
        __syncthreads();

        // ---- prefetch next tile (latency hidden behind compute) ----
        if (kt + 64 < S) {
            #pragma unroll
            for (int j = 0; j < 2; ++j) {
                int slot = j * 256 + tid;
                int r = slot >> 3, c = slot & 7;
                kp[j] = *(const uint4*)&Kb[(size_t)(kt + 64 + r) * H + h * DH + c * 8];
                vp[j] = *(const uint4*)&VT[(size_t)(h * DH + r) * S + kt + 64 + c * 8];
            }
            pbp = *(const uint4*)&PBg[(size_t)(q0 + pq) * S + kt + 64 + pc];
        }

        // ---- QK^T/8 (Q pre-scaled) ----
        f32x4 sc[4];
        #pragma unroll
        for (int nt = 0; nt < 4; ++nt) {
            bf16x8 bk0 = *(const bf16x8*)&Ks[nt * 16 + l15][quad * 8];
            bf16x8 bk1 = *(const bf16x8*)&Ks[nt * 16 + l15][32 + quad * 8];
            f32x4 c = (f32x4)0.f;
            c = __builtin_amdgcn_mfma_f32_16x16x32_bf16(aq0, bk0, c, 0, 0, 0);
            c = __builtin_amdgcn_mfma_f32_16x16x32_bf16(aq1, bk1, c, 0, 0, 0);
            sc[nt] = c;
        }
        // ---- inline rel+mask bias from packed byte (C layout) ----
        #pragma unroll
        for (int nt = 0; nt < 4; ++nt)
            #pragma unroll
            for (int r = 0; r < 4; ++r) {
                int row = w * 16 + quad * 4 + r;
                unsigned char b = U.main.PB[row][nt * 16 + l15];
                float rl = Rl[row][b & 63];
                float mt = (b & 0x80) ? -10000.0f : 0.0f;
                sc[nt][r] = sc[nt][r] + rl + mt;
            }

        // ---- online softmax ----
        float alpha[4];
        #pragma unroll
        for (int r = 0; r < 4; ++r) {
            float v = fmaxf(fmaxf(sc[0][r], sc[1][r]), fmaxf(sc[2][r], sc[3][r]));
            v = fmaxf(v, __shfl_xor(v, 1, 64));
            v = fmaxf(v, __shfl_xor(v, 2, 64));
            v = fmaxf(v, __shfl_xor(v, 4, 64));
            v = fmaxf(v, __shfl_xor(v, 8, 64));
            float mnew = fmaxf(mrow[r], v);
            alpha[r] = __expf(mrow[r] - mnew);
            mrow[r] = mnew;
        }
        float rsum[4] = {0.f, 0.f, 0.f, 0.f};
        #pragma unroll
        for (int nt = 0; nt < 4; ++nt)
            #pragma unroll
            for (int r = 0; r < 4; ++r) {
                float p = __expf(sc[nt][r] - mrow[r]);
                sc[nt][r] = p;
                rsum[r] += p;
            }
        #pragma unroll
        for (int r = 0; r < 4; ++r) {
            float v = rsum[r];
            v += __shfl_xor(v, 1, 64);
            v += __shfl_xor(v, 2, 64);
            v += __shfl_xor(v, 4, 64);
            v += __shfl_xor(v, 8, 64);
            lrow[r] = lrow[r] * alpha[r] + v;
            #pragma unroll
            for (int dt = 0; dt < 4; ++dt) O[dt][r] *= alpha[r];
        }

        // ---- P -> LDS (wave-private rows) ----
        #pragma unroll
        for (int nt = 0; nt < 4; ++nt)
            #pragma unroll
            for (int r = 0; r < 4; ++r)
                ((unsigned short*)&U.main.Ps[w * 16 + quad * 4 + r][nt * 16 + l15])[0] =
                    f2bbits(sc[nt][r]);

        // ---- P.V accumulate ----
        bf16x8 ap0 = *(const bf16x8*)&U.main.Ps[w * 16 + l15][quad * 8];
        bf16x8 ap1 = *(const bf16x8*)&U.main.Ps[w * 16 + l15][32 + quad * 8];
        #pragma unroll
        for (int dt = 0; dt < 4; ++dt) {
            bf16x8 bv0 = *(const bf16x8*)&Vs[dt * 16 + l15][quad * 8];
            bf16x8 bv1 = *(const bf16x8*)&Vs[dt * 16 + l15][32 + quad * 8];
            O[dt] = __builtin_amdgcn_mfma_f32_16x16x32_bf16(ap0, bv0, O[dt], 0, 0, 0);
            O[dt] = __builtin_amdgcn_mfma_f32_16x16x32_bf16(ap1, bv1, O[dt], 0, 0, 0);
        }
        __syncthreads();
    }

    #pragma unroll
    for (int r = 0; r < 4; ++r) {
        int q = q0 + w * 16 + quad * 4 + r;
        float inv = 1.0f / lrow[r];
        #pragma unroll
        for (int dt = 0; dt < 4; ++dt)
            Cb[(size_t)q * H + h * DH + dt * 16 + l15] = __float2bfloat16(O[dt][r] * inv);
    }
}

extern "C" void kernel_launch(void* const* d_in, const int* in_sizes, int n_in,
                              void* d_out, int out_size, void* d_ws, size_t ws_size,
                              hipStream_t stream)
{
    const void* x        = d_in[0];
    const int*  att_mask = (const int*)d_in[1];
    const int*  rel_ids  = (const int*)d_in[2];
    const void* Wq = d_in[3];
    const void* bq = d_in[4];
    const void* Wk = d_in[5];
    const void* bk = d_in[6];
    const void* Wv = d_in[7];
    const void* bv = d_in[8];
    const void* rel_emb  = d_in[9];
    const void* rel_bias = d_in[10];
    const void* Wo = d_in[11];
    const void* bo = d_in[12];

    char* p = (char*)d_ws;
    bf16* xb  = (bf16*)p; p += (size_t)S * H * 2;
    bf16* WTq = (bf16*)p; p += (size_t)H * H * 2;
    bf16* WTk = (bf16*)p; p += (size_t)H * H * 2;
    bf16* WTv = (bf16*)p; p += (size_t)H * H * 2;
    bf16* WoT = (bf16*)p; p += (size_t)H * H * 2;
    bf16* Qb  = (bf16*)p; p += (size_t)S * H * 2;
    bf16* Kb  = (bf16*)p; p += (size_t)S * H * 2;
    bf16* Vb  = (bf16*)p; p += (size_t)S * H * 2;
    bf16* VT  = (bf16*)p; p += (size_t)S * H * 2;
    bf16* Cb  = (bf16*)p; p += (size_t)S * H * 2;
    unsigned char* PBg = (unsigned char*)p; p += (size_t)S * S;
    int* flag = (int*)p;

    detect_dtype<<<1, 256, 0, stream>>>((const unsigned int*)x, flag);

    pack_rm<<<(S * S) / 1024, 256, 0, stream>>>(rel_ids, att_mask, PBg);
    convert_x<<<(S * H) / 1024, 256, 0, stream>>>(x, xb, flag);
    wtrans<<<dim3(H / 64, H / 64, 4), 256, 0, stream>>>(
        Wq, Wk, Wv, Wo, WTq, WTk, WTv, WoT, flag);

    qkv_mfma<<<dim3(H / 128, S / 128, 3), 256, 0, stream>>>(
        xb, WTq, WTk, WTv, bq, bk, bv, Qb, Kb, Vb, flag);

    vtrans<<<dim3(S / 64, H / 64), 256, 0, stream>>>(Vb, VT);

    attn_mfma<<<dim3(NH, S / 64), 256, 0, stream>>>(
        Qb, Kb, VT, rel_emb, rel_bias, PBg, Cb, flag);

    out_mfma<<<dim3(H / 128, S / 128), 256, 0, stream>>>(Cb, WoT, bo, d_out, flag);
}

// Round 8
// 267.063 us; speedup vs baseline: 1.0338x; 1.0338x over previous
//
#include <hip/hip_runtime.h>
#include <hip/hip_bf16.h>

#define S 2048
#define H 1024
#define NH 16
#define DH 64
#define RV 32
#define BK 32
#define NSPLIT 2
#define SKEYS (S / NSPLIT)

typedef __hip_bfloat16 bf16;
typedef short bf16x8 __attribute__((ext_vector_type(8)));
typedef float f32x4 __attribute__((ext_vector_type(4)));

__device__ __forceinline__ float b2f(bf16 v) { return __bfloat162float(v); }
__device__ __forceinline__ unsigned short f2bbits(float x) {
    __hip_bfloat16 b = __float2bfloat16(x);
    return *reinterpret_cast<unsigned short*>(&b);
}
// Flexible load: f==1 -> buffer holds fp32, f==0 -> buffer holds bf16.
__device__ __forceinline__ float ldf(const void* p, int i, int f) {
    return f ? ((const float*)p)[i] : b2f(((const bf16*)p)[i]);
}
// async 16B global -> LDS (lane l lands at lds_base + l*16)
__device__ __forceinline__ void gl_lds16(const bf16* g, bf16* l) {
    __builtin_amdgcn_global_load_lds(
        (const __attribute__((address_space(1))) void*)g,
        (__attribute__((address_space(3))) void*)l,
        16, 0, 0);
}

// ---------------- dtype sniffer -------------------------------------------
__global__ void detect_dtype(const unsigned int* __restrict__ xw,
                             int* __restrict__ flag)
{
    __shared__ int cnt;
    if (threadIdx.x == 0) cnt = 0;
    __syncthreads();
    unsigned int w = xw[threadIdx.x];
    unsigned int ex = ((w & 0xffffu) >> 7) & 0xffu;
    int big = (ex > 134u) ? 1 : 0;
    #pragma unroll
    for (int off = 32; off > 0; off >>= 1) big += __shfl_xor(big, off, 64);
    if ((threadIdx.x & 63) == 0) atomicAdd(&cnt, big);
    __syncthreads();
    if (threadIdx.x == 0) *flag = (cnt > 60) ? 1 : 0;
}

// ---------------- pack rel_ids + att_mask into one byte, TRANSPOSED --------
// PBTg[k][q] = rid | (mask==0)<<7.  Read coalesced along k, transpose via LDS.
__global__ __launch_bounds__(256) void pack_rm_t(
    const int* __restrict__ rel_ids, const int* __restrict__ att_mask,
    unsigned char* __restrict__ PBTg)
{
    __shared__ unsigned char Tb[64][68];
    const int t = threadIdx.x;
    const int k0 = blockIdx.x * 64;
    const int q0 = blockIdx.y * 64;
    {
        int q = t >> 2, kc = (t & 3) * 16;
        const int* rp = rel_ids + (size_t)(q0 + q) * S + k0 + kc;
        const int* mp = att_mask + (size_t)(q0 + q) * S + k0 + kc;
        #pragma unroll
        for (int j = 0; j < 4; ++j) {
            int4 rid = ((const int4*)rp)[j];
            int4 msk = ((const int4*)mp)[j];
            uchar4 o;
            o.x = (unsigned char)(rid.x | ((msk.x == 0) << 7));
            o.y = (unsigned char)(rid.y | ((msk.y == 0) << 7));
            o.z = (unsigned char)(rid.z | ((msk.z == 0) << 7));
            o.w = (unsigned char)(rid.w | ((msk.w == 0) << 7));
            *(uchar4*)&Tb[q][kc + j * 4] = o;
        }
    }
    __syncthreads();
    {
        int kk = t >> 2, qq = (t & 3) * 16;
        unsigned char ob[16];
        #pragma unroll
        for (int j = 0; j < 16; ++j) ob[j] = Tb[qq + j][kk];
        *(uint4*)&PBTg[(size_t)(k0 + kk) * S + q0 + qq] = *(uint4*)ob;
    }
}

// ---------------- input conversion ----------------------------------------
__global__ __launch_bounds__(256) void convert_x(
    const void* __restrict__ x, bf16* __restrict__ xb,
    const int* __restrict__ flag)
{
    const int i = (blockIdx.x * 256 + threadIdx.x) * 4;
    if (*flag) {
        float4 v = ((const float4*)x)[i >> 2];
        ushort4 o;
        o.x = f2bbits(v.x); o.y = f2bbits(v.y);
        o.z = f2bbits(v.z); o.w = f2bbits(v.w);
        *(ushort4*)&xb[i] = o;
    } else {
        ((ushort4*)xb)[i >> 2] = ((const ushort4*)x)[i >> 2];
    }
}

// transpose-convert weights: W[k][n] (fp32 or bf16) -> WT[n][k] bf16
__global__ __launch_bounds__(256) void wtrans(
    const void* __restrict__ W0, const void* __restrict__ W1,
    const void* __restrict__ W2, const void* __restrict__ W3,
    bf16* __restrict__ T0, bf16* __restrict__ T1,
    bf16* __restrict__ T2, bf16* __restrict__ T3,
    const int* __restrict__ flag)
{
    const void* W; bf16* T;
    switch (blockIdx.z) {
        case 0:  W = W0; T = T0; break;
        case 1:  W = W1; T = T1; break;
        case 2:  W = W2; T = T2; break;
        default: W = W3; T = T3; break;
    }
    const int f = *flag;
    __shared__ unsigned short Ts[64][68];
    const int t = threadIdx.x;
    const int tx = t & 15, ty = t >> 4;
    const int n0 = blockIdx.x * 64;
    const int k0 = blockIdx.y * 64;
    #pragma unroll
    for (int it = 0; it < 4; ++it) {
        int k = ty + it * 16;
        int base = (k0 + k) * H + n0 + tx * 4;
        #pragma unroll
        for (int e = 0; e < 4; ++e)
            Ts[k][tx * 4 + e] = f2bbits(ldf(W, base + e, f));
    }
    __syncthreads();
    #pragma unroll
    for (int it = 0; it < 4; ++it) {
        int n = ty + it * 16;
        ushort4 o;
        o.x = Ts[tx * 4 + 0][n];
        o.y = Ts[tx * 4 + 1][n];
        o.z = Ts[tx * 4 + 2][n];
        o.w = Ts[tx * 4 + 3][n];
        *(ushort4*)&T[(size_t)(n0 + n) * H + k0 + tx * 4] = o;
    }
}

// transpose Vb[S][H] bf16 -> VT[H][S] bf16
__global__ __launch_bounds__(256) void vtrans(
    const bf16* __restrict__ Vb, bf16* __restrict__ VT)
{
    __shared__ unsigned short Ts[64][68];
    const int t = threadIdx.x;
    const int tx = t & 15, ty = t >> 4;
    const int s0 = blockIdx.x * 64;
    const int h0 = blockIdx.y * 64;
    #pragma unroll
    for (int it = 0; it < 4; ++it) {
        int s = ty + it * 16;
        *(ushort4*)&Ts[s][tx * 4] =
            *(const ushort4*)&Vb[(size_t)(s0 + s) * H + h0 + tx * 4];
    }
    __syncthreads();
    #pragma unroll
    for (int it = 0; it < 4; ++it) {
        int hh = ty + it * 16;
        ushort4 o;
        o.x = Ts[tx * 4 + 0][hh];
        o.y = Ts[tx * 4 + 1][hh];
        o.z = Ts[tx * 4 + 2][hh];
        o.w = Ts[tx * 4 + 3][hh];
        *(ushort4*)&VT[(size_t)(h0 + hh) * S + s0 + tx * 4] = o;
    }
}

// ---------------- m97-style 128x128 MFMA GEMM core -------------------------
__device__ __forceinline__ void gemm128_bt(
    const bf16* __restrict__ A, const bf16* __restrict__ BT,
    f32x4 (&acc)[4][4])
{
    const int tid = threadIdx.x;
    const int w = tid >> 6, lane = tid & 63;
    const int l15 = lane & 15, quad = lane >> 4;
    const int wm = (w & 1) * 64, wn = (w >> 1) * 64;
    const int rowb = blockIdx.y * 128;
    const int colb = blockIdx.x * 128;

    __shared__ bf16 As[128 * BK];   // [m][k], rows of 32 bf16 (64 B)
    __shared__ bf16 Bs[128 * BK];   // [n][k]

    for (int kb = 0; kb < H; kb += BK) {
        #pragma unroll
        for (int j = 0; j < 2; ++j) {
            int i = j * 256 + w * 64 + lane;
            gl_lds16(&A[(size_t)(rowb + (i >> 2)) * H + kb + (i & 3) * 8],
                     &As[(size_t)(j * 256 + w * 64) * 8]);
            gl_lds16(&BT[(size_t)(colb + (i >> 2)) * H + kb + (i & 3) * 8],
                     &Bs[(size_t)(j * 256 + w * 64) * 8]);
        }
        __syncthreads();

        bf16x8 af[4], bfr[4];
        #pragma unroll
        for (int mt = 0; mt < 4; ++mt)
            af[mt] = *(const bf16x8*)&As[(wm + mt * 16 + l15) * BK + quad * 8];
        #pragma unroll
        for (int nt = 0; nt < 4; ++nt)
            bfr[nt] = *(const bf16x8*)&Bs[(wn + nt * 16 + l15) * BK + quad * 8];
        #pragma unroll
        for (int mt = 0; mt < 4; ++mt)
            #pragma unroll
            for (int nt = 0; nt < 4; ++nt)
                acc[mt][nt] = __builtin_amdgcn_mfma_f32_16x16x32_bf16(
                    af[mt], bfr[nt], acc[mt][nt], 0, 0, 0);
        __syncthreads();
    }
}

// ---------------- QKV MFMA GEMM -------------------------------------------
__global__ __launch_bounds__(256) void qkv_mfma(
    const bf16* __restrict__ xb,
    const bf16* __restrict__ WTq, const bf16* __restrict__ WTk,
    const bf16* __restrict__ WTv,
    const void* __restrict__ bq, const void* __restrict__ bk,
    const void* __restrict__ bv,
    bf16* __restrict__ Qb, bf16* __restrict__ Kb, bf16* __restrict__ Vb,
    const int* __restrict__ flag)
{
    const bf16* BT; const void* bias; bf16* out;
    if (blockIdx.z == 0)      { BT = WTq; bias = bq; out = Qb; }
    else if (blockIdx.z == 1) { BT = WTk; bias = bk; out = Kb; }
    else                      { BT = WTv; bias = bv; out = Vb; }
    const int f = *flag;

    f32x4 acc[4][4];
    #pragma unroll
    for (int a = 0; a < 4; ++a)
        #pragma unroll
        for (int b = 0; b < 4; ++b) acc[a][b] = (f32x4)0.f;

    gemm128_bt(xb, BT, acc);

    const int tid = threadIdx.x;
    const int w = tid >> 6, lane = tid & 63;
    const int l15 = lane & 15, quad = lane >> 4;
    const int wm = (w & 1) * 64, wn = (w >> 1) * 64;
    const int rowb = blockIdx.y * 128;
    const int colb = blockIdx.x * 128;

    float bvv[4];
    #pragma unroll
    for (int nt = 0; nt < 4; ++nt)
        bvv[nt] = ldf(bias, colb + wn + nt * 16 + l15, f);

    #pragma unroll
    for (int mt = 0; mt < 4; ++mt)
        #pragma unroll
        for (int nt = 0; nt < 4; ++nt)
            #pragma unroll
            for (int r = 0; r < 4; ++r) {
                int m = rowb + wm + mt * 16 + quad * 4 + r;
                int n = colb + wn + nt * 16 + l15;
                out[(size_t)m * H + n] = __float2bfloat16(acc[mt][nt][r] + bvv[nt]);
            }
}

// ---------------- output MFMA GEMM ----------------------------------------
__global__ __launch_bounds__(256) void out_mfma(
    const bf16* __restrict__ Cb, const bf16* __restrict__ WoT,
    const void* __restrict__ bias, void* __restrict__ out,
    const int* __restrict__ flag)
{
    const int f = *flag;
    f32x4 acc[4][4];
    #pragma unroll
    for (int a = 0; a < 4; ++a)
        #pragma unroll
        for (int b = 0; b < 4; ++b) acc[a][b] = (f32x4)0.f;

    gemm128_bt(Cb, WoT, acc);

    const int tid = threadIdx.x;
    const int w = tid >> 6, lane = tid & 63;
    const int l15 = lane & 15, quad = lane >> 4;
    const int wm = (w & 1) * 64, wn = (w >> 1) * 64;
    const int rowb = blockIdx.y * 128;
    const int colb = blockIdx.x * 128;

    float bvv[4];
    #pragma unroll
    for (int nt = 0; nt < 4; ++nt)
        bvv[nt] = ldf(bias, colb + wn + nt * 16 + l15, f);

    #pragma unroll
    for (int mt = 0; mt < 4; ++mt)
        #pragma unroll
        for (int nt = 0; nt < 4; ++nt)
            #pragma unroll
            for (int r = 0; r < 4; ++r) {
                int m = rowb + wm + mt * 16 + quad * 4 + r;
                int n = colb + wn + nt * 16 + l15;
                float v = acc[mt][nt][r] + bvv[nt];
                if (f) ((float*)out)[(size_t)m * H + n] = v;
                else   ((bf16*)out)[(size_t)m * H + n] = __float2bfloat16(v);
            }
}

// ---------------- MFMA flash attention, SPLIT-K over keys -------------------
// block = (64 q) x (1 head) x (1 split of SKEYS keys). 4 waves.
// Writes un-normalized partial O (fp32) + m + l; reduce_splits merges.
// LDS ~40 KB -> 4 blocks/CU; grid 1024 blocks = exactly 4/CU.
__global__ __launch_bounds__(256, 4) void attn_mfma(
    const bf16* __restrict__ Qb, const bf16* __restrict__ Kb,
    const bf16* __restrict__ VT,
    const void* __restrict__ rel_emb, const void* __restrict__ rel_bias,
    const unsigned char* __restrict__ PBTg,
    float* __restrict__ Op, float* __restrict__ Mp, float* __restrict__ Lp,
    const int* __restrict__ flag)
{
    const int h = blockIdx.x;
    const int qb = blockIdx.y;
    const int split = blockIdx.z;
    const int q0 = qb * 64;
    const int kt0 = split * SKEYS;
    const int tid = threadIdx.x;
    const int w = tid >> 6;
    const int lane = tid & 63;
    const int l15 = lane & 15;
    const int quad = lane >> 4;
    const int f = *flag;

    __shared__ short Ks[64][72];
    __shared__ short Vs[64][72];
    __shared__ float Rl[64][33];     // pre-scaled rel scores (incl bias/8)
    __shared__ float Rbias[32];
    union SharedU {
        struct { short Qs[64][72]; short Es[32][72]; } init;
        struct { short Ps[64][72]; unsigned char PBT[64][72]; } main;  // PBT[key][q]
    };
    __shared__ SharedU U;

    // ---- prefetch tile 0 into registers (start latency early) ----
    uint4 kp[2], vp[2], pbp;
    const int pkk = tid >> 2, pqq = (tid & 3) * 16;
    {
        #pragma unroll
        for (int j = 0; j < 2; ++j) {
            int slot = j * 256 + tid;
            int r = slot >> 3, c = slot & 7;
            kp[j] = *(const uint4*)&Kb[(size_t)(kt0 + r) * H + h * DH + c * 8];
            vp[j] = *(const uint4*)&VT[(size_t)(h * DH + r) * S + kt0 + c * 8];
        }
        pbp = *(const uint4*)&PBTg[(size_t)(kt0 + pkk) * S + q0 + pqq];
    }

    // ---- stage Q (scaled by 0.125) + rel_emb + rel_bias ----
    for (int slot = tid; slot < 512; slot += 256) {
        int q = slot >> 3, c = slot & 7;
        uint4 raw = *(const uint4*)&Qb[(size_t)(q0 + q) * H + h * DH + c * 8];
        const unsigned short* rs = (const unsigned short*)&raw;
        unsigned short os[8];
        #pragma unroll
        for (int e = 0; e < 8; ++e) {
            float v; *((unsigned int*)&v) = ((unsigned int)rs[e]) << 16;
            os[e] = f2bbits(v * 0.125f);            // exact: exponent shift
        }
        *(ushort4*)&U.init.Qs[q][c * 8]     = *(ushort4*)&os[0];
        *(ushort4*)&U.init.Qs[q][c * 8 + 4] = *(ushort4*)&os[4];
    }
    {
        int r = tid >> 3, c8 = (tid & 7) * 8;
        if (f) {
            const float* src = (const float*)rel_emb + (r * NH + h) * DH + c8;
            ushort4 o0, o1;
            o0.x = f2bbits(src[0]); o0.y = f2bbits(src[1]);
            o0.z = f2bbits(src[2]); o0.w = f2bbits(src[3]);
            o1.x = f2bbits(src[4]); o1.y = f2bbits(src[5]);
            o1.z = f2bbits(src[6]); o1.w = f2bbits(src[7]);
            *(ushort4*)&U.init.Es[r][c8] = o0;
            *(ushort4*)&U.init.Es[r][c8 + 4] = o1;
        } else {
            *(uint4*)&U.init.Es[r][c8] =
                *(const uint4*)((const bf16*)rel_emb + (r * NH + h) * DH + c8);
        }
        if (tid < RV) Rbias[tid] = ldf(rel_bias, tid * NH + h, f) * 0.125f;
    }
    __syncthreads();

    // ---- Q fragments (scaled; reused everywhere) ----
    bf16x8 aq0 = *(const bf16x8*)&U.init.Qs[w * 16 + l15][quad * 8];
    bf16x8 aq1 = *(const bf16x8*)&U.init.Qs[w * 16 + l15][32 + quad * 8];

    // ---- Rl[q][r] = (Q/8) . rel_emb^T + rel_bias/8 via MFMA ----
    #pragma unroll
    for (int nt = 0; nt < 2; ++nt) {
        bf16x8 be0 = *(const bf16x8*)&U.init.Es[nt * 16 + l15][quad * 8];
        bf16x8 be1 = *(const bf16x8*)&U.init.Es[nt * 16 + l15][32 + quad * 8];
        f32x4 c = (f32x4)0.f;
        c = __builtin_amdgcn_mfma_f32_16x16x32_bf16(aq0, be0, c, 0, 0, 0);
        c = __builtin_amdgcn_mfma_f32_16x16x32_bf16(aq1, be1, c, 0, 0, 0);
        float rb = Rbias[nt * 16 + l15];
        #pragma unroll
        for (int r = 0; r < 4; ++r)
            Rl[w * 16 + quad * 4 + r][nt * 16 + l15] = c[r] + rb;
    }
    __syncthreads();   // everyone done with Qs/Es before Ps/PBT overwrite them

    f32x4 O[4];
    float mrow[4], lrow[4];
    #pragma unroll
    for (int i = 0; i < 4; ++i) { O[i] = (f32x4)0.f; mrow[i] = -1e30f; lrow[i] = 0.f; }

    for (int kt = kt0; kt < kt0 + SKEYS; kt += 64) {
        // ---- store prefetched tile to LDS ----
        #pragma unroll
        for (int j = 0; j < 2; ++j) {
            int slot = j * 256 + tid;
            int r = slot >> 3, c = slot & 7;
            *(uint4*)&Ks[r][c * 8] = kp[j];
            *(uint4*)&Vs[r][c * 8] = vp[j];
        }
        *(uint2*)&U.main.PBT[pkk][pqq]     = make_uint2(pbp.x, pbp.y);
        *(uint2*)&U.main.PBT[pkk][pqq + 8] = make_uint2(pbp.z, pbp.w);
        __syncthreads();

        // ---- prefetch next tile (latency hidden behind compute) ----
        if (kt + 64 < kt0 + SKEYS) {
            #pragma unroll
            for (int j = 0; j < 2; ++j) {
                int slot = j * 256 + tid;
                int r = slot >> 3, c = slot & 7;
                kp[j] = *(const uint4*)&Kb[(size_t)(kt + 64 + r) * H + h * DH + c * 8];
                vp[j] = *(const uint4*)&VT[(size_t)(h * DH + r) * S + kt + 64 + c * 8];
            }
            pbp = *(const uint4*)&PBTg[(size_t)(kt + 64 + pkk) * S + q0 + pqq];
        }

        // ---- QK^T/8 (Q pre-scaled) ----
        f32x4 sc[4];
        #pragma unroll
        for (int nt = 0; nt < 4; ++nt) {
            bf16x8 bk0 = *(const bf16x8*)&Ks[nt * 16 + l15][quad * 8];
            bf16x8 bk1 = *(const bf16x8*)&Ks[nt * 16 + l15][32 + quad * 8];
            f32x4 c = (f32x4)0.f;
            c = __builtin_amdgcn_mfma_f32_16x16x32_bf16(aq0, bk0, c, 0, 0, 0);
            c = __builtin_amdgcn_mfma_f32_16x16x32_bf16(aq1, bk1, c, 0, 0, 0);
            sc[nt] = c;
        }
        // ---- inline rel+mask bias: one dword per nt from transposed PBT ----
        #pragma unroll
        for (int nt = 0; nt < 4; ++nt) {
            unsigned int pw =
                *(const unsigned int*)&U.main.PBT[nt * 16 + l15][w * 16 + quad * 4];
            #pragma unroll
            for (int r = 0; r < 4; ++r) {
                int row = w * 16 + quad * 4 + r;
                unsigned int b = (pw >> (8 * r)) & 0xffu;
                float rl = Rl[row][b & 63u];
                float mt = (b & 0x80u) ? -10000.0f : 0.0f;
                sc[nt][r] = sc[nt][r] + rl + mt;
            }
        }

        // ---- online softmax ----
        float alpha[4];
        #pragma unroll
        for (int r = 0; r < 4; ++r) {
            float v = fmaxf(fmaxf(sc[0][r], sc[1][r]), fmaxf(sc[2][r], sc[3][r]));
            v = fmaxf(v, __shfl_xor(v, 1, 64));
            v = fmaxf(v, __shfl_xor(v, 2, 64));
            v = fmaxf(v, __shfl_xor(v, 4, 64));
            v = fmaxf(v, __shfl_xor(v, 8, 64));
            float mnew = fmaxf(mrow[r], v);
            alpha[r] = __expf(mrow[r] - mnew);
            mrow[r] = mnew;
        }
        float rsum[4] = {0.f, 0.f, 0.f, 0.f};
        #pragma unroll
        for (int nt = 0; nt < 4; ++nt)
            #pragma unroll
            for (int r = 0; r < 4; ++r) {
                float p = __expf(sc[nt][r] - mrow[r]);
                sc[nt][r] = p;
                rsum[r] += p;
            }
        #pragma unroll
        for (int r = 0; r < 4; ++r) {
            float v = rsum[r];
            v += __shfl_xor(v, 1, 64);
            v += __shfl_xor(v, 2, 64);
            v += __shfl_xor(v, 4, 64);
            v += __shfl_xor(v, 8, 64);
            lrow[r] = lrow[r] * alpha[r] + v;
            #pragma unroll
            for (int dt = 0; dt < 4; ++dt) O[dt][r] *= alpha[r];
        }

        // ---- P -> LDS (wave-private rows) ----
        #pragma unroll
        for (int nt = 0; nt < 4; ++nt)
            #pragma unroll
            for (int r = 0; r < 4; ++r)
                ((unsigned short*)&U.main.Ps[w * 16 + quad * 4 + r][nt * 16 + l15])[0] =
                    f2bbits(sc[nt][r]);

        // ---- P.V accumulate ----
        bf16x8 ap0 = *(const bf16x8*)&U.main.Ps[w * 16 + l15][quad * 8];
        bf16x8 ap1 = *(const bf16x8*)&U.main.Ps[w * 16 + l15][32 + quad * 8];
        #pragma unroll
        for (int dt = 0; dt < 4; ++dt) {
            bf16x8 bv0 = *(const bf16x8*)&Vs[dt * 16 + l15][quad * 8];
            bf16x8 bv1 = *(const bf16x8*)&Vs[dt * 16 + l15][32 + quad * 8];
            O[dt] = __builtin_amdgcn_mfma_f32_16x16x32_bf16(ap0, bv0, O[dt], 0, 0, 0);
            O[dt] = __builtin_amdgcn_mfma_f32_16x16x32_bf16(ap1, bv1, O[dt], 0, 0, 0);
        }
        __syncthreads();
    }

    // ---- write partials (un-normalized O, m, l) ----
    const size_t base = ((size_t)split * NH + h) * 32 + qb;
    float* Ob = Op + base * 4096;
    #pragma unroll
    for (int r = 0; r < 4; ++r) {
        int qr = w * 16 + quad * 4 + r;
        #pragma unroll
        for (int dt = 0; dt < 4; ++dt)
            Ob[qr * 64 + dt * 16 + l15] = O[dt][r];
        if (l15 == 0) {
            Mp[base * 64 + qr] = mrow[r];
            Lp[base * 64 + qr] = lrow[r];
        }
    }
}

// ---------------- merge split partials -> Cb bf16 --------------------------
__global__ __launch_bounds__(256) void reduce_splits(
    const float* __restrict__ Op, const float* __restrict__ Mp,
    const float* __restrict__ Lp, bf16* __restrict__ Cb)
{
    const int h = blockIdx.x;
    const int qb = blockIdx.y;
    const int q0 = qb * 64;
    const int tid = threadIdx.x;
    const int q = tid >> 2;
    const int d0 = (tid & 3) * 16;

    const size_t b0 = ((size_t)0 * NH + h) * 32 + qb;
    const size_t b1 = ((size_t)1 * NH + h) * 32 + qb;

    float m0 = Mp[b0 * 64 + q], m1 = Mp[b1 * 64 + q];
    float mx = fmaxf(m0, m1);
    float a0 = __expf(m0 - mx), a1 = __expf(m1 - mx);
    float l = a0 * Lp[b0 * 64 + q] + a1 * Lp[b1 * 64 + q];
    float inv = 1.0f / l;
    a0 *= inv; a1 *= inv;

    const float4* O0 = (const float4*)(Op + b0 * 4096 + q * 64 + d0);
    const float4* O1 = (const float4*)(Op + b1 * 4096 + q * 64 + d0);
    bf16* outp = Cb + (size_t)(q0 + q) * H + h * DH + d0;
    #pragma unroll
    for (int j = 0; j < 4; ++j) {
        float4 v0 = O0[j], v1 = O1[j];
        ushort4 o;
        o.x = f2bbits(a0 * v0.x + a1 * v1.x);
        o.y = f2bbits(a0 * v0.y + a1 * v1.y);
        o.z = f2bbits(a0 * v0.z + a1 * v1.z);
        o.w = f2bbits(a0 * v0.w + a1 * v1.w);
        *(ushort4*)&outp[j * 4] = o;
    }
}

extern "C" void kernel_launch(void* const* d_in, const int* in_sizes, int n_in,
                              void* d_out, int out_size, void* d_ws, size_t ws_size,
                              hipStream_t stream)
{
    const void* x        = d_in[0];
    const int*  att_mask = (const int*)d_in[1];
    const int*  rel_ids  = (const int*)d_in[2];
    const void* Wq = d_in[3];
    const void* bq = d_in[4];
    const void* Wk = d_in[5];
    const void* bk = d_in[6];
    const void* Wv = d_in[7];
    const void* bv = d_in[8];
    const void* rel_emb  = d_in[9];
    const void* rel_bias = d_in[10];
    const void* Wo = d_in[11];
    const void* bo = d_in[12];

    char* p = (char*)d_ws;
    bf16* xb  = (bf16*)p; p += (size_t)S * H * 2;
    bf16* WTq = (bf16*)p; p += (size_t)H * H * 2;
    bf16* WTk = (bf16*)p; p += (size_t)H * H * 2;
    bf16* WTv = (bf16*)p; p += (size_t)H * H * 2;
    bf16* WoT = (bf16*)p; p += (size_t)H * H * 2;
    bf16* Qb  = (bf16*)p; p += (size_t)S * H * 2;
    bf16* Kb  = (bf16*)p; p += (size_t)S * H * 2;
    bf16* Vb  = (bf16*)p; p += (size_t)S * H * 2;
    bf16* VT  = (bf16*)p; p += (size_t)S * H * 2;
    bf16* Cb  = (bf16*)p; p += (size_t)S * H * 2;
    unsigned char* PBTg = (unsigned char*)p; p += (size_t)S * S;
    float* Op = (float*)p; p += (size_t)NSPLIT * NH * 32 * 64 * 64 * 4;
    float* Mp = (float*)p; p += (size_t)NSPLIT * NH * 32 * 64 * 4;
    float* Lp = (float*)p; p += (size_t)NSPLIT * NH * 32 * 64 * 4;
    int* flag = (int*)p;

    detect_dtype<<<1, 256, 0, stream>>>((const unsigned int*)x, flag);

    pack_rm_t<<<dim3(S / 64, S / 64), 256, 0, stream>>>(rel_ids, att_mask, PBTg);
    convert_x<<<(S * H) / 1024, 256, 0, stream>>>(x, xb, flag);
    wtrans<<<dim3(H / 64, H / 64, 4), 256, 0, stream>>>(
        Wq, Wk, Wv, Wo, WTq, WTk, WTv, WoT, flag);

    qkv_mfma<<<dim3(H / 128, S / 128, 3), 256, 0, stream>>>(
        xb, WTq, WTk, WTv, bq, bk, bv, Qb, Kb, Vb, flag);

    vtrans<<<dim3(S / 64, H / 64), 256, 0, stream>>>(Vb, VT);

    attn_mfma<<<dim3(NH, S / 64, NSPLIT), 256, 0, stream>>>(
        Qb, Kb, VT, rel_emb, rel_bias, PBTg, Op, Mp, Lp, flag);

    reduce_splits<<<dim3(NH, S / 64), 256, 0, stream>>>(Op, Mp, Lp, Cb);

    out_mfma<<<dim3(H / 128, S / 128), 256, 0, stream>>>(Cb, WoT, bo, d_out, flag);
}